// Round 4
// baseline (330.051 us; speedup 1.0000x reference)
//
#include <hip/hip_runtime.h>
#include <math.h>

#define N_NODES 20000
#define N_EDGES 320000
#define EMB 128
#define HID 512          // 4*EMB
#define NCHUNK ((N_NODES + 1023) / 1024)   // 20

// fused_edge geometry (round-2 champion): 128-thr blocks (2 waves), each wave
// owns 4 consecutive rows.
#define RPW 4
#define WPB 2
#define RPB (RPW * WPB)                    // 8
#define FE_BLOCKS ((N_NODES + RPB - 1) / RPB)  // 2500

// MFMA gemm geometry
#define GEMM_MT ((N_NODES + 127) / 128)    // 157
#define GEMM_MFMA_BLOCKS (GEMM_MT * 8)     // 1256 (8 n-tiles of 128 over N=1024)

// prep kernel block ranges
#define PREP_H_BLOCKS 2500                 // 20000*128/4 float4 / 256thr
#define PREP_W_BLOCKS 512                  // 1024*128 elems / 256thr
#define HIST_BLOCKS ((N_EDGES + 255) / 256) // 1250
#define PREP_HIST_OFF (PREP_H_BLOCKS + PREP_W_BLOCKS)      // 3012
#define PREP_BLOCKS (PREP_HIST_OFF + HIST_BLOCKS)          // 4262

typedef __attribute__((ext_vector_type(8))) short bf16x8;  // 8 bf16 = 4 VGPR
typedef __attribute__((ext_vector_type(4))) float f32x4;

#define MFMA16(a, b, c) __builtin_amdgcn_mfma_f32_16x16x32_bf16((a), (b), (c), 0, 0, 0)

// ---------------------------------------------------------------------------
__global__ void init_deg(int* __restrict__ deg, int* __restrict__ offs) {
    int i = blockIdx.x * 256 + threadIdx.x;
    if (i < N_NODES) deg[i] = 0;
    if (i == 0) offs[N_NODES] = N_EDGES;
}

// ---------------------------------------------------------------------------
// bf16x3 split helpers (round-to-nearest-even bf16; exact residual chain):
// x = f(s1) + f(s2) + f(s3) + O(2^-24 |x|)
// ---------------------------------------------------------------------------
__device__ __forceinline__ unsigned short bf16rn(float x) {
    unsigned u = __builtin_bit_cast(unsigned, x);
    u += 0x7FFFu + ((u >> 16) & 1u);
    return (unsigned short)(u >> 16);
}
__device__ __forceinline__ float bf2f(unsigned short b) {
    unsigned u = ((unsigned)b) << 16;
    return __builtin_bit_cast(float, u);
}
__device__ __forceinline__ void split3(float x, unsigned short& s1,
                                       unsigned short& s2, unsigned short& s3) {
    s1 = bf16rn(x);
    float r = x - bf2f(s1);
    s2 = bf16rn(r);
    float r2 = r - bf2f(s2);
    s3 = bf16rn(r2);
}

// ---------------------------------------------------------------------------
// prep_hist: heterogeneous grid.
//  [0, 2500):        h [20000][128] fp32 -> hs1/2/3 bf16 (same layout)
//  [2500, 3012):     W1 [256][512] fp32 -> wt1/2/3 bf16 TRANSPOSED [1024][128]
//                    (row n: n<512 -> W1[k][n] (P half); n>=512 -> W1[128+k][n-512])
//                    Transposed so MFMA B-fragments are contiguous 16B/lane.
//  [3012, 4262):     row histogram (moved out of the old gemm_hist)
// ---------------------------------------------------------------------------
__global__ __launch_bounds__(256) void prep_hist(
    const float* __restrict__ h, const float* __restrict__ W1,
    unsigned short* __restrict__ hs1, unsigned short* __restrict__ hs2,
    unsigned short* __restrict__ hs3,
    unsigned short* __restrict__ wt1, unsigned short* __restrict__ wt2,
    unsigned short* __restrict__ wt3,
    const int* __restrict__ row, int* __restrict__ deg)
{
    const int bid = blockIdx.x, tid = threadIdx.x;

    if (bid < PREP_H_BLOCKS) {
        const int i4 = bid * 256 + tid;              // float4 index, exact fit
        const float4 v = ((const float4*)h)[i4];
        unsigned short a1[4], a2[4], a3[4];
        split3(v.x, a1[0], a2[0], a3[0]);
        split3(v.y, a1[1], a2[1], a3[1]);
        split3(v.z, a1[2], a2[2], a3[2]);
        split3(v.w, a1[3], a2[3], a3[3]);
#define PACK4(dst, a) { \
            uint2 pk; \
            pk.x = (unsigned)a[0] | ((unsigned)a[1] << 16); \
            pk.y = (unsigned)a[2] | ((unsigned)a[3] << 16); \
            *(uint2*)((dst) + (size_t)i4 * 4) = pk; }
        PACK4(hs1, a1); PACK4(hs2, a2); PACK4(hs3, a3);
#undef PACK4
        return;
    }

    if (bid < PREP_HIST_OFF) {
        const int t = (bid - PREP_H_BLOCKS) * 256 + tid;   // exact fit 131072
        const int k = t & 127, n = t >> 7;                 // n in [0,1024)
        const float x = W1[(size_t)(((n >> 9) << 7) + k) * HID + (n & 511)];
        unsigned short s1, s2, s3;
        split3(x, s1, s2, s3);
        wt1[t] = s1; wt2[t] = s2; wt3[t] = s3;
        return;
    }

    const int e = (bid - PREP_HIST_OFF) * 256 + tid;
    if (e < N_EDGES) atomicAdd(&deg[row[e]], 1);
}

// ---------------------------------------------------------------------------
// gemm_mfma: O[20000][1024] = h @ [W1a | W1b] via bf16x3-split MFMA.
// 6 cross products (11,12,21,22,13,31) -> fp32-accurate to ~1.2e-7 rel.
// Block: 256 thr (4 waves), tile 128(M)x128(N), K=128 in 4 k-steps of 32.
// Wave w: rows [w*32, w*32+32) as 2 m-subtiles of 16; 8 n-subtiles of 16.
// Verified fragment layout (learn_hip m89):
//   A: lane l -> A[l&15][ks*32 + (l>>4)*8 + j]   (row-major hs, 16B/lane)
//   B: lane l -> B[ks*32 + (l>>4)*8 + j][l&15]   (= row l&15 of TRANSPOSED wt)
//   D: lane l, reg r -> row (l>>4)*4 + r, col l&15
// No LDS: B tiles are block-uniform -> L1/L2 catch the reuse.
// ---------------------------------------------------------------------------
__global__ __launch_bounds__(256) void gemm_mfma(
    const unsigned short* __restrict__ hs1, const unsigned short* __restrict__ hs2,
    const unsigned short* __restrict__ hs3,
    const unsigned short* __restrict__ wt1, const unsigned short* __restrict__ wt2,
    const unsigned short* __restrict__ wt3,
    const float* __restrict__ b1, float* __restrict__ P, float* __restrict__ Q)
{
    const int bid = blockIdx.x;
    const int nt = bid & 7, mt = bid >> 3;
    const int m_base = mt * 128;
    const int tid = threadIdx.x, lane = tid & 63, w = tid >> 6;
    const int l15 = lane & 15, l4 = lane >> 4;

    int ar0 = m_base + w * 32 + l15;          // m-subtile 0 source row
    int ar1 = ar0 + 16;                       // m-subtile 1 source row
    if (ar0 > N_NODES - 1) ar0 = N_NODES - 1; // clamp (stores are guarded)
    if (ar1 > N_NODES - 1) ar1 = N_NODES - 1;
    const size_t ao0 = (size_t)ar0 * 128 + l4 * 8;
    const size_t ao1 = (size_t)ar1 * 128 + l4 * 8;
    const size_t bo  = (size_t)(nt * 128 + l15) * 128 + l4 * 8;

    f32x4 acc[2][8];
#pragma unroll
    for (int m = 0; m < 2; ++m)
#pragma unroll
        for (int n = 0; n < 8; ++n) acc[m][n] = (f32x4){0.f, 0.f, 0.f, 0.f};

#pragma unroll
    for (int ks = 0; ks < 4; ++ks) {
        const int ko = ks * 32;
        const bf16x8 a10 = *(const bf16x8*)(hs1 + ao0 + ko);
        const bf16x8 a20 = *(const bf16x8*)(hs2 + ao0 + ko);
        const bf16x8 a30 = *(const bf16x8*)(hs3 + ao0 + ko);
        const bf16x8 a11 = *(const bf16x8*)(hs1 + ao1 + ko);
        const bf16x8 a21 = *(const bf16x8*)(hs2 + ao1 + ko);
        const bf16x8 a31 = *(const bf16x8*)(hs3 + ao1 + ko);
#pragma unroll
        for (int n0 = 0; n0 < 8; ++n0) {
            const int off = n0 * 2048 + ko;   // n0*16 rows * 128 k
            const bf16x8 bv1 = *(const bf16x8*)(wt1 + bo + off);
            const bf16x8 bv2 = *(const bf16x8*)(wt2 + bo + off);
            const bf16x8 bv3 = *(const bf16x8*)(wt3 + bo + off);
            acc[0][n0] = MFMA16(a10, bv1, acc[0][n0]);
            acc[0][n0] = MFMA16(a10, bv2, acc[0][n0]);
            acc[0][n0] = MFMA16(a20, bv1, acc[0][n0]);
            acc[0][n0] = MFMA16(a20, bv2, acc[0][n0]);
            acc[0][n0] = MFMA16(a10, bv3, acc[0][n0]);
            acc[0][n0] = MFMA16(a30, bv1, acc[0][n0]);
            acc[1][n0] = MFMA16(a11, bv1, acc[1][n0]);
            acc[1][n0] = MFMA16(a11, bv2, acc[1][n0]);
            acc[1][n0] = MFMA16(a21, bv1, acc[1][n0]);
            acc[1][n0] = MFMA16(a21, bv2, acc[1][n0]);
            acc[1][n0] = MFMA16(a11, bv3, acc[1][n0]);
            acc[1][n0] = MFMA16(a31, bv1, acc[1][n0]);
        }
    }

    const bool isP = nt < 4;
    float* __restrict__ dst = isP ? P : Q;
    const int colb = (nt & 3) * 128;
#pragma unroll
    for (int n0 = 0; n0 < 8; ++n0) {
        const int col = colb + n0 * 16 + l15;
        const float bias = isP ? b1[col] : 0.0f;
#pragma unroll
        for (int m = 0; m < 2; ++m) {
            const int rbase = m_base + w * 32 + m * 16 + l4 * 4;
#pragma unroll
            for (int r = 0; r < 4; ++r) {
                const int rr = rbase + r;
                if (rr < N_NODES)
                    dst[(size_t)rr * HID + col] = acc[m][n0][r] + bias;
            }
        }
    }
}

// ---------------------------------------------------------------------------
__device__ __forceinline__ int wave_incl_scan(int v, int lane) {
#pragma unroll
    for (int off = 1; off < 64; off <<= 1) {
        int t = __shfl_up(v, off, 64);
        if (lane >= off) v += t;
    }
    return v;
}

__global__ __launch_bounds__(1024) void scan_part(const int* __restrict__ deg,
                                                  int* __restrict__ part,
                                                  int* __restrict__ totals) {
    __shared__ int wsum[16];
    const int tid = threadIdx.x, lane = tid & 63, w = tid >> 6;
    const int i = blockIdx.x * 1024 + tid;
    int v = (i < N_NODES) ? deg[i] : 0;
    int incl = wave_incl_scan(v, lane);
    if (lane == 63) wsum[w] = incl;
    __syncthreads();
    if (w == 0) {
        int x = (lane < 16) ? wsum[lane] : 0;
        int xs = wave_incl_scan(x, lane);
        if (lane < 16) wsum[lane] = xs - x;
        if (lane == 15) totals[blockIdx.x] = xs;
    }
    __syncthreads();
    if (i < N_NODES) part[i] = wsum[w] + incl - v;
}

__global__ __launch_bounds__(1024) void scan_apply(const int* __restrict__ part,
                                                   const int* __restrict__ totals,
                                                   int* __restrict__ cursor,
                                                   int* __restrict__ offs) {
    __shared__ int carry_s;
    const int tid = threadIdx.x;
    if (tid < 64) {
        int v = (tid < NCHUNK) ? totals[tid] : 0;
        int incl = wave_incl_scan(v, tid);
        if (tid == (int)blockIdx.x) carry_s = incl - v;   // exclusive carry
    }
    __syncthreads();
    const int i = blockIdx.x * 1024 + tid;
    if (i < N_NODES) {
        int o = part[i] + carry_s;
        cursor[i] = o;
        offs[i] = o;
    }
}

// ---------------------------------------------------------------------------
// scatter: cols16[pos] = col (u16) in CSR order; inv[e] = pos so unperm runs
// in ORIGINAL edge order with coalesced output writes.
// ---------------------------------------------------------------------------
__global__ void scatter_edges(const int* __restrict__ row, const int* __restrict__ col,
                              int* __restrict__ cursor,
                              unsigned short* __restrict__ cols16,
                              int* __restrict__ inv) {
    int e = blockIdx.x * 256 + threadIdx.x;
    if (e >= N_EDGES) return;
    int r = row[e];
    int pos = atomicAdd(&cursor[r], 1);
    cols16[pos] = (unsigned short)col[e];
    inv[e] = pos;
}

// ---------------------------------------------------------------------------
// Fused edge phase — round-2 champion, restored verbatim (101.5us, 42% occ).
// The LDS-ring variant (r3) regressed: per-edge serialization + occupancy.
// FETCH (311MB = 8 XCD x Q) is at its floor; this kernel is at its
// memory-path ceiling.
// ---------------------------------------------------------------------------
__device__ __forceinline__ float dot8_relu(const float4 qa, const float4 qb,
                                           const float4 p0, const float4 p1,
                                           const float4 w0, const float4 w1) {
    float t = 0.0f;
    t = fmaf(fmaxf(p0.x + qa.x, 0.0f), w0.x, t);
    t = fmaf(fmaxf(p0.y + qa.y, 0.0f), w0.y, t);
    t = fmaf(fmaxf(p0.z + qa.z, 0.0f), w0.z, t);
    t = fmaf(fmaxf(p0.w + qa.w, 0.0f), w0.w, t);
    t = fmaf(fmaxf(p1.x + qb.x, 0.0f), w1.x, t);
    t = fmaf(fmaxf(p1.y + qb.y, 0.0f), w1.y, t);
    t = fmaf(fmaxf(p1.z + qb.z, 0.0f), w1.z, t);
    t = fmaf(fmaxf(p1.w + qb.w, 0.0f), w1.w, t);
    return t;
}

__device__ __forceinline__ float chunk_scores(
    const float* __restrict__ Q, const unsigned short* __restrict__ cols16,
    int es_base, int nch, int lane, int j0,
    const float4 p0, const float4 p1, const float4 w0, const float4 w1,
    float bias2)
{
    int mycol = 0;
    if (lane < nch) mycol = (int)cols16[es_base + lane];
    float mysc = -INFINITY;

#define QL2(k, bb, d0, d1) { \
        int c_ = __shfl(mycol, (bb) + (k), 64); \
        const float* __restrict__ q_ = Q + (size_t)c_ * HID; \
        d0 = *(const float4*)(q_ + j0); \
        d1 = *(const float4*)(q_ + 256 + j0); }

    float4 a00, a01, a10, a11;
    QL2(0, 0, a00, a01); QL2(1, 0, a10, a11);

    for (int b = 0; b < nch; b += 2) {
        float4 n00, n01, n10, n11;
        const bool more = (b + 2) < nch;
        if (more) { QL2(0, b + 2, n00, n01); QL2(1, b + 2, n10, n11); }

        float s0 = dot8_relu(a00, a01, p0, p1, w0, w1);
        float s1 = dot8_relu(a10, a11, p0, p1, w0, w1);

#pragma unroll
        for (int off = 32; off > 0; off >>= 1) {
            s0 += __shfl_xor(s0, off, 64);
            s1 += __shfl_xor(s1, off, 64);
        }

        const int k = lane - b;
        if ((unsigned)k < 2u && lane < nch) mysc = (k ? s1 : s0) + bias2;

        if (more) { a00 = n00; a01 = n01; a10 = n10; a11 = n11; }
    }
#undef QL2
    return mysc;
}

__global__ __launch_bounds__(128) void fused_edge(
    const float* __restrict__ P, const float* __restrict__ Q,
    const float* __restrict__ W2, const float* __restrict__ b2,
    const unsigned short* __restrict__ cols16, const int* __restrict__ offs,
    float2* __restrict__ tmp)
{
    const int tid = threadIdx.x, lane = tid & 63, w = tid >> 6;
    const int r0 = blockIdx.x * RPB + w * RPW;
    const int r1 = (r0 + RPW < N_NODES) ? r0 + RPW : N_NODES;
    const int j0 = lane << 2;

    const float4 w0 = *(const float4*)(W2 + j0);
    const float4 w1 = *(const float4*)(W2 + 256 + j0);
    const float bias2 = b2[0];

    for (int r = r0; r < r1; ++r) {
        const int es = offs[r], ee = offs[r + 1];
        const int d = ee - es;
        if (d == 0) continue;

        const float* __restrict__ prow = P + (size_t)r * HID;
        const float4 p0 = *(const float4*)(prow + j0);
        const float4 p1 = *(const float4*)(prow + 256 + j0);

        if (d <= 64) {
            float mysc = chunk_scores(Q, cols16, es, d, lane, j0,
                                      p0, p1, w0, w1, bias2);

            float m = mysc;
#pragma unroll
            for (int off = 32; off > 0; off >>= 1)
                m = fmaxf(m, __shfl_xor(m, off, 64));

            float ev = (lane < d) ? expf(mysc - m) : 0.0f;
            float ssum = ev;
#pragma unroll
            for (int off = 32; off > 0; off >>= 1)
                ssum += __shfl_xor(ssum, off, 64);

            if (lane < d) {
                float p = ev / ssum;
                float logits = logf(p) - log1pf(-p);   // +inf when p==1 (d==1)
                tmp[es + lane] = make_float2(mysc, logits);
            }
        } else {
            for (int base = 0; base < d; base += 64) {
                const int nch = (d - base < 64) ? d - base : 64;
                float mysc = chunk_scores(Q, cols16, es + base, nch, lane, j0,
                                          p0, p1, w0, w1, bias2);
                if (lane < nch) tmp[es + base + lane].x = mysc;
            }

            float m = -INFINITY;
            for (int j = lane; j < d; j += 64)
                m = fmaxf(m, tmp[es + j].x);
#pragma unroll
            for (int off = 32; off > 0; off >>= 1)
                m = fmaxf(m, __shfl_xor(m, off, 64));

            float ssum = 0.0f;
            for (int j = lane; j < d; j += 64)
                ssum += expf(tmp[es + j].x - m);
#pragma unroll
            for (int off = 32; off > 0; off >>= 1)
                ssum += __shfl_xor(ssum, off, 64);

            for (int j = lane; j < d; j += 64) {
                float s = tmp[es + j].x;
                float p = expf(s - m) / ssum;
                float logits = logf(p) - log1pf(-p);
                tmp[es + j] = make_float2(s, logits);
            }
        }
    }
}

// ---------------------------------------------------------------------------
// unperm: original-edge-order tail. Sequential u/edge_mask/inv reads, one 8B
// gather from the L2-resident tmp (2.56 MB), fully coalesced writes of all 5
// outputs.
// ---------------------------------------------------------------------------
__global__ __launch_bounds__(256) void unperm(
    const float2* __restrict__ tmp, const int* __restrict__ inv,
    const float* __restrict__ u, const int* __restrict__ edge_mask,
    const int* __restrict__ hierarchy,
    float* __restrict__ scores, float* __restrict__ out_y,
    float* __restrict__ out_mask, float* __restrict__ out_causal,
    float* __restrict__ out_spu)
{
    const int e = blockIdx.x * 256 + threadIdx.x;
    if (e >= N_EDGES) return;
    const float2 t = tmp[inv[e]];
    const float s = t.x;
    const float uu = u[e];
    const float L = logf(uu) - log1pf(-uu);
    const float y = 1.0f / (1.0f + expf(-(t.y + L)));
    const bool hard = y > 0.5f;                    // ST forward value == y_hard
    const int mm = hard ? (hierarchy[0] + 1) : edge_mask[e];
    scores[e]     = s;
    out_y[e]      = hard ? 1.0f : 0.0f;
    out_mask[e]   = (float)mm;
    out_causal[e] = (mm > 0)   ?  s : 0.0f;
    out_spu[e]    = (mm == -1) ? -s : 0.0f;
}

// ---------------------------------------------------------------------------
extern "C" void kernel_launch(void* const* d_in, const int* in_sizes, int n_in,
                              void* d_out, int out_size, void* d_ws, size_t ws_size,
                              hipStream_t stream) {
    const float* h_ptr = (const float*)d_in[0];
    const float* W1    = (const float*)d_in[1];
    const float* b1    = (const float*)d_in[2];
    const float* W2    = (const float*)d_in[3];
    const float* b2    = (const float*)d_in[4];
    const float* u     = (const float*)d_in[5];
    const int*   row   = (const int*)d_in[6];
    const int*   col   = (const int*)d_in[7];
    const int*   emask = (const int*)d_in[8];
    const int*   hier  = (const int*)d_in[9];

    float* out        = (float*)d_out;
    float* scores     = out;                        // [E]
    float* out_y      = out + (size_t)N_EDGES;      // [E]
    float* out_mask   = out + 2 * (size_t)N_EDGES;  // [E]
    float* out_causal = out + 3 * (size_t)N_EDGES;  // [E]
    float* out_spu    = out + 4 * (size_t)N_EDGES;  // [E]

    // workspace: P, Q fp32 (16B align); hs1..3 bf16 [20000][128]; wt1..3 bf16
    // [1024][128]; then small int arrays. tmp/cols16/inv ALIAS the hs region
    // (hs dead after gemm_mfma; tmp/cols16/inv first written by scatter_edges
    // which runs after) -> saves 4.5MB.
    float*          P      = (float*)d_ws;
    float*          Qm     = P + (size_t)N_NODES * HID;
    unsigned short* hs1    = (unsigned short*)(Qm + (size_t)N_NODES * HID);
    unsigned short* hs2    = hs1 + (size_t)N_NODES * EMB;
    unsigned short* hs3    = hs2 + (size_t)N_NODES * EMB;
    unsigned short* wt1    = hs3 + (size_t)N_NODES * EMB;
    unsigned short* wt2    = wt1 + 1024 * 128;
    unsigned short* wt3    = wt2 + 1024 * 128;
    int*            deg    = (int*)(wt3 + 1024 * 128);
    int*            cursor = deg + N_NODES;
    int*            offs   = cursor + N_NODES;      // [N_NODES+1]
    int*            part   = offs + N_NODES + 1;
    int*            totals = part + N_NODES;        // [NCHUNK]
    // aliases into the hs region (safe: first write is scatter_edges /
    // fused_edge, both after gemm_mfma's last hs read)
    float2*         tmp    = (float2*)hs1;                      // [E] 2.56MB
    unsigned short* cols16 = (unsigned short*)(tmp + N_EDGES);  // [E] u16
    int*            inv    = (int*)(cols16 + N_EDGES);          // [E]

    hipLaunchKernelGGL(init_deg, dim3((N_NODES + 255) / 256), dim3(256), 0, stream,
                       deg, offs);

    hipLaunchKernelGGL(prep_hist, dim3(PREP_BLOCKS), dim3(256), 0, stream,
                       h_ptr, W1, hs1, hs2, hs3, wt1, wt2, wt3, row, deg);

    hipLaunchKernelGGL(gemm_mfma, dim3(GEMM_MFMA_BLOCKS), dim3(256), 0, stream,
                       hs1, hs2, hs3, wt1, wt2, wt3, b1, P, Qm);

    hipLaunchKernelGGL(scan_part, dim3(NCHUNK), dim3(1024), 0, stream, deg, part, totals);
    hipLaunchKernelGGL(scan_apply, dim3(NCHUNK), dim3(1024), 0, stream,
                       part, totals, cursor, offs);
    hipLaunchKernelGGL(scatter_edges, dim3((N_EDGES + 255) / 256), dim3(256), 0, stream,
                       row, col, cursor, cols16, inv);

    hipLaunchKernelGGL(fused_edge, dim3(FE_BLOCKS), dim3(128), 0, stream,
                       P, Qm, W2, b2, cols16, offs, tmp);

    hipLaunchKernelGGL(unperm, dim3((N_EDGES + 255) / 256), dim3(256), 0, stream,
                       tmp, inv, u, emask, hier,
                       scores, out_y, out_mask, out_causal, out_spu);
}

// Round 5
// 279.320 us; speedup vs baseline: 1.1816x; 1.1816x over previous
//
#include <hip/hip_runtime.h>
#include <math.h>

#define N_NODES 20000
#define N_EDGES 320000
#define EMB 128
#define HID 512          // 4*EMB
#define NCHUNK ((N_NODES + 1023) / 1024)   // 20

// fused_edge geometry (round-2 champion)
#define RPW 4
#define WPB 2
#define RPB (RPW * WPB)                    // 8
#define FE_BLOCKS ((N_NODES + RPB - 1) / RPB)  // 2500

// MFMA gemm geometry: 128x128 tile, 2x2 waves of 64x64
#define GEMM_MT ((N_NODES + 127) / 128)    // 157
#define GEMM_MFMA_BLOCKS (GEMM_MT * 8)     // 1256
#define HIST_BLOCKS ((N_EDGES + 255) / 256) // 1250
#define GH_BLOCKS (GEMM_MFMA_BLOCKS + HIST_BLOCKS)  // 2506
#define N_HTILES (N_NODES / 16)            // 1250 (exact)

// prep (pack-only) block ranges
#define PREP_H_BLOCKS 2500                 // 20000*128/4 float4 / 256thr
#define PREP_W_BLOCKS 512                  // 1024*128 / 256thr
#define PREP_BLOCKS (PREP_H_BLOCKS + PREP_W_BLOCKS)   // 3012

typedef __attribute__((ext_vector_type(8))) short bf16x8;  // 8 bf16 = 4 VGPR
typedef __attribute__((ext_vector_type(4))) float f32x4;

#define MFMA16(a, b, c) __builtin_amdgcn_mfma_f32_16x16x32_bf16((a), (b), (c), 0, 0, 0)

// ---------------------------------------------------------------------------
__global__ void init_deg(int* __restrict__ deg, int* __restrict__ offs) {
    int i = blockIdx.x * 256 + threadIdx.x;
    if (i < N_NODES) deg[i] = 0;
    if (i == 0) offs[N_NODES] = N_EDGES;
}

// ---------------------------------------------------------------------------
// bf16x3 split helpers (round-to-nearest-even bf16; exact residual chain)
// ---------------------------------------------------------------------------
__device__ __forceinline__ unsigned short bf16rn(float x) {
    unsigned u = __builtin_bit_cast(unsigned, x);
    u += 0x7FFFu + ((u >> 16) & 1u);
    return (unsigned short)(u >> 16);
}
__device__ __forceinline__ float bf2f(unsigned short b) {
    unsigned u = ((unsigned)b) << 16;
    return __builtin_bit_cast(float, u);
}
__device__ __forceinline__ void split3(float x, unsigned short& s1,
                                       unsigned short& s2, unsigned short& s3) {
    s1 = bf16rn(x);
    float r = x - bf2f(s1);
    s2 = bf16rn(r);
    float r2 = r - bf2f(s2);
    s3 = bf16rn(r2);
}

// ---------------------------------------------------------------------------
// prep_pack: write splits in PACKED-FRAGMENT layout so every MFMA fragment
// load in gemm_mfma is base + lane*16B (lane-contiguous, zero divergence).
// Packed element (t, ks, lane, j) at offset (t*4+ks)*512 + lane*8 + j where
//   source row r = t*16 + (lane&15), k = ks*32 + (lane>>4)*8 + j.
// Same for W (transposed: packed "row" n = output col, k = W1 row index).
// ---------------------------------------------------------------------------
__global__ __launch_bounds__(256) void prep_pack(
    const float* __restrict__ h, const float* __restrict__ W1,
    unsigned short* __restrict__ hp1, unsigned short* __restrict__ hp2,
    unsigned short* __restrict__ hp3,
    unsigned short* __restrict__ wp1, unsigned short* __restrict__ wp2,
    unsigned short* __restrict__ wp3)
{
    const int bid = blockIdx.x, tid = threadIdx.x;

    if (bid < PREP_H_BLOCKS) {
        const int i4 = bid * 256 + tid;              // float4 index, exact fit
        const float4 v = ((const float4*)h)[i4];
        const int r  = i4 >> 5;                      // 32 float4 per row
        const int k0 = (i4 & 31) << 2;
        const int t = r >> 4, rowi = r & 15;
        const int ks = k0 >> 5;
        const int ln = (((k0 >> 3) & 3) << 4) + rowi;
        const int j0 = k0 & 7;                       // 0 or 4 -> 8B aligned
        const size_t off = (size_t)((t * 4 + ks) * 512) + ln * 8 + j0;
        unsigned short a1[4], a2[4], a3[4];
        split3(v.x, a1[0], a2[0], a3[0]);
        split3(v.y, a1[1], a2[1], a3[1]);
        split3(v.z, a1[2], a2[2], a3[2]);
        split3(v.w, a1[3], a2[3], a3[3]);
#define PACK4(dst, a) { \
            uint2 pk; \
            pk.x = (unsigned)a[0] | ((unsigned)a[1] << 16); \
            pk.y = (unsigned)a[2] | ((unsigned)a[3] << 16); \
            *(uint2*)((dst) + off) = pk; }
        PACK4(hp1, a1); PACK4(hp2, a2); PACK4(hp3, a3);
#undef PACK4
        return;
    }

    // W path: t over 1024 cols x 128 k, n-minor for coalesced W1 reads
    const int t = (bid - PREP_H_BLOCKS) * 256 + tid;   // exact fit 131072
    const int n = t & 1023, k = t >> 10;
    const float x = W1[(size_t)(((n >> 9) << 7) + k) * HID + (n & 511)];
    unsigned short s1, s2, s3;
    split3(x, s1, s2, s3);
    const int tn = n >> 4, rown = n & 15;
    const int ks = k >> 5;
    const int ln = (((k >> 3) & 3) << 4) + rown;
    const int j = k & 7;
    const size_t off = (size_t)((tn * 4 + ks) * 512) + ln * 8 + j;
    wp1[off] = s1; wp2[off] = s2; wp3[off] = s3;
}

// ---------------------------------------------------------------------------
// gemm_mfma + histogram (heterogeneous blocks; hist rides on idle CUs again).
// O[20000][1024] = h @ [W1a|W1b] via bf16x3-split MFMA (6 cross products:
// 11,12,21,22,13,31 -> fp32-accurate ~1.2e-7 rel; same order as r4 = passed).
// Block 256thr/4 waves as 2x2; wave = 64x64 output (4 m-sub x 4 n-sub of 16).
// Per ks: 12 A frag loads (held) + per-n-tile 3 B loads DOUBLE-BUFFERED so
// ~24 MFMAs cover each B group's latency. All frag loads lane-contiguous 1KB.
// ---------------------------------------------------------------------------
__global__ __launch_bounds__(256) void gemm_mfma(
    const unsigned short* __restrict__ hp1, const unsigned short* __restrict__ hp2,
    const unsigned short* __restrict__ hp3,
    const unsigned short* __restrict__ wp1, const unsigned short* __restrict__ wp2,
    const unsigned short* __restrict__ wp3,
    const float* __restrict__ b1, float* __restrict__ P, float* __restrict__ Q,
    const int* __restrict__ row, int* __restrict__ deg)
{
    const int bid = blockIdx.x;
    const int tid = threadIdx.x;

    if (bid >= GEMM_MFMA_BLOCKS) {
        // ---- histogram path ----
        const int e = (bid - GEMM_MFMA_BLOCKS) * 256 + tid;
        if (e < N_EDGES) atomicAdd(&deg[row[e]], 1);
        return;
    }

    const int nt = bid & 7, mt = bid >> 3;   // 8 consecutive blocks share mt -> A L2/L3 reuse
    const int lane = tid & 63, w = tid >> 6;
    const int wm = w >> 1, wn = w & 1;
    const int l15 = lane & 15, l4 = lane >> 4;

    int tA[4];
#pragma unroll
    for (int i = 0; i < 4; ++i) {
        int t = mt * 8 + wm * 4 + i;
        tA[i] = (t < N_HTILES) ? t : N_HTILES - 1;   // clamp; stores guarded
    }
    const int tB0 = nt * 8 + wn * 4;                 // <= 60, always in range

    f32x4 acc[4][4];
#pragma unroll
    for (int i = 0; i < 4; ++i)
#pragma unroll
        for (int j = 0; j < 4; ++j) acc[i][j] = (f32x4){0.f, 0.f, 0.f, 0.f};

    const size_t lo = (size_t)lane * 8;

#pragma unroll
    for (int ks = 0; ks < 4; ++ks) {
        bf16x8 A1[4], A2[4], A3[4];
#pragma unroll
        for (int i = 0; i < 4; ++i) {
            const size_t ao = (size_t)((tA[i] * 4 + ks) * 512) + lo;
            A1[i] = *(const bf16x8*)(hp1 + ao);
            A2[i] = *(const bf16x8*)(hp2 + ao);
            A3[i] = *(const bf16x8*)(hp3 + ao);
        }
        const size_t b_base = (size_t)((tB0 * 4 + ks) * 512) + lo;
        bf16x8 Ba1 = *(const bf16x8*)(wp1 + b_base);
        bf16x8 Ba2 = *(const bf16x8*)(wp2 + b_base);
        bf16x8 Ba3 = *(const bf16x8*)(wp3 + b_base);
#pragma unroll
        for (int jn = 0; jn < 4; ++jn) {
            bf16x8 Bn1, Bn2, Bn3;
            if (jn < 3) {   // prefetch next n-tile (tile stride = 2048 shorts)
                const size_t bo = b_base + (size_t)(jn + 1) * 2048;
                Bn1 = *(const bf16x8*)(wp1 + bo);
                Bn2 = *(const bf16x8*)(wp2 + bo);
                Bn3 = *(const bf16x8*)(wp3 + bo);
            }
#pragma unroll
            for (int i = 0; i < 4; ++i) {
                acc[i][jn] = MFMA16(A1[i], Ba1, acc[i][jn]);
                acc[i][jn] = MFMA16(A1[i], Ba2, acc[i][jn]);
                acc[i][jn] = MFMA16(A2[i], Ba1, acc[i][jn]);
                acc[i][jn] = MFMA16(A2[i], Ba2, acc[i][jn]);
                acc[i][jn] = MFMA16(A1[i], Ba3, acc[i][jn]);
                acc[i][jn] = MFMA16(A3[i], Ba1, acc[i][jn]);
            }
            if (jn < 3) { Ba1 = Bn1; Ba2 = Bn2; Ba3 = Bn3; }
        }
    }

    // store: D lane l, reg r -> row (l>>4)*4+r, col l&15 (m89-verified)
    const int rbase = mt * 128 + wm * 64 + l4 * 4;
#pragma unroll
    for (int jn = 0; jn < 4; ++jn) {
        const int n = nt * 128 + wn * 64 + jn * 16 + l15;
        const bool isP = n < 512;
        float* __restrict__ dst = isP ? P : Q;
        const int col = n & 511;
        const float bias = isP ? b1[col] : 0.0f;
#pragma unroll
        for (int i = 0; i < 4; ++i) {
            const int rr0 = rbase + i * 16;
#pragma unroll
            for (int r = 0; r < 4; ++r) {
                const int rr = rr0 + r;
                if (rr < N_NODES)
                    dst[(size_t)rr * HID + col] = acc[i][jn][r] + bias;
            }
        }
    }
}

// ---------------------------------------------------------------------------
__device__ __forceinline__ int wave_incl_scan(int v, int lane) {
#pragma unroll
    for (int off = 1; off < 64; off <<= 1) {
        int t = __shfl_up(v, off, 64);
        if (lane >= off) v += t;
    }
    return v;
}

__global__ __launch_bounds__(1024) void scan_part(const int* __restrict__ deg,
                                                  int* __restrict__ part,
                                                  int* __restrict__ totals) {
    __shared__ int wsum[16];
    const int tid = threadIdx.x, lane = tid & 63, w = tid >> 6;
    const int i = blockIdx.x * 1024 + tid;
    int v = (i < N_NODES) ? deg[i] : 0;
    int incl = wave_incl_scan(v, lane);
    if (lane == 63) wsum[w] = incl;
    __syncthreads();
    if (w == 0) {
        int x = (lane < 16) ? wsum[lane] : 0;
        int xs = wave_incl_scan(x, lane);
        if (lane < 16) wsum[lane] = xs - x;
        if (lane == 15) totals[blockIdx.x] = xs;
    }
    __syncthreads();
    if (i < N_NODES) part[i] = wsum[w] + incl - v;
}

__global__ __launch_bounds__(1024) void scan_apply(const int* __restrict__ part,
                                                   const int* __restrict__ totals,
                                                   int* __restrict__ cursor,
                                                   int* __restrict__ offs) {
    __shared__ int carry_s;
    const int tid = threadIdx.x;
    if (tid < 64) {
        int v = (tid < NCHUNK) ? totals[tid] : 0;
        int incl = wave_incl_scan(v, tid);
        if (tid == (int)blockIdx.x) carry_s = incl - v;   // exclusive carry
    }
    __syncthreads();
    const int i = blockIdx.x * 1024 + tid;
    if (i < N_NODES) {
        int o = part[i] + carry_s;
        cursor[i] = o;
        offs[i] = o;
    }
}

// ---------------------------------------------------------------------------
__global__ void scatter_edges(const int* __restrict__ row, const int* __restrict__ col,
                              int* __restrict__ cursor,
                              unsigned short* __restrict__ cols16,
                              int* __restrict__ inv) {
    int e = blockIdx.x * 256 + threadIdx.x;
    if (e >= N_EDGES) return;
    int r = row[e];
    int pos = atomicAdd(&cursor[r], 1);
    cols16[pos] = (unsigned short)col[e];
    inv[e] = pos;
}

// ---------------------------------------------------------------------------
// Fused edge phase — round-2 champion (101.5us, at its 8xXCD-L2-fill memory
// ceiling: FETCH pinned at 311MB across three structures).
// ---------------------------------------------------------------------------
__device__ __forceinline__ float dot8_relu(const float4 qa, const float4 qb,
                                           const float4 p0, const float4 p1,
                                           const float4 w0, const float4 w1) {
    float t = 0.0f;
    t = fmaf(fmaxf(p0.x + qa.x, 0.0f), w0.x, t);
    t = fmaf(fmaxf(p0.y + qa.y, 0.0f), w0.y, t);
    t = fmaf(fmaxf(p0.z + qa.z, 0.0f), w0.z, t);
    t = fmaf(fmaxf(p0.w + qa.w, 0.0f), w0.w, t);
    t = fmaf(fmaxf(p1.x + qb.x, 0.0f), w1.x, t);
    t = fmaf(fmaxf(p1.y + qb.y, 0.0f), w1.y, t);
    t = fmaf(fmaxf(p1.z + qb.z, 0.0f), w1.z, t);
    t = fmaf(fmaxf(p1.w + qb.w, 0.0f), w1.w, t);
    return t;
}

__device__ __forceinline__ float chunk_scores(
    const float* __restrict__ Q, const unsigned short* __restrict__ cols16,
    int es_base, int nch, int lane, int j0,
    const float4 p0, const float4 p1, const float4 w0, const float4 w1,
    float bias2)
{
    int mycol = 0;
    if (lane < nch) mycol = (int)cols16[es_base + lane];
    float mysc = -INFINITY;

#define QL2(k, bb, d0, d1) { \
        int c_ = __shfl(mycol, (bb) + (k), 64); \
        const float* __restrict__ q_ = Q + (size_t)c_ * HID; \
        d0 = *(const float4*)(q_ + j0); \
        d1 = *(const float4*)(q_ + 256 + j0); }

    float4 a00, a01, a10, a11;
    QL2(0, 0, a00, a01); QL2(1, 0, a10, a11);

    for (int b = 0; b < nch; b += 2) {
        float4 n00, n01, n10, n11;
        const bool more = (b + 2) < nch;
        if (more) { QL2(0, b + 2, n00, n01); QL2(1, b + 2, n10, n11); }

        float s0 = dot8_relu(a00, a01, p0, p1, w0, w1);
        float s1 = dot8_relu(a10, a11, p0, p1, w0, w1);

#pragma unroll
        for (int off = 32; off > 0; off >>= 1) {
            s0 += __shfl_xor(s0, off, 64);
            s1 += __shfl_xor(s1, off, 64);
        }

        const int k = lane - b;
        if ((unsigned)k < 2u && lane < nch) mysc = (k ? s1 : s0) + bias2;

        if (more) { a00 = n00; a01 = n01; a10 = n10; a11 = n11; }
    }
#undef QL2
    return mysc;
}

__global__ __launch_bounds__(128) void fused_edge(
    const float* __restrict__ P, const float* __restrict__ Q,
    const float* __restrict__ W2, const float* __restrict__ b2,
    const unsigned short* __restrict__ cols16, const int* __restrict__ offs,
    float2* __restrict__ tmp)
{
    const int tid = threadIdx.x, lane = tid & 63, w = tid >> 6;
    const int r0 = blockIdx.x * RPB + w * RPW;
    const int r1 = (r0 + RPW < N_NODES) ? r0 + RPW : N_NODES;
    const int j0 = lane << 2;

    const float4 w0 = *(const float4*)(W2 + j0);
    const float4 w1 = *(const float4*)(W2 + 256 + j0);
    const float bias2 = b2[0];

    for (int r = r0; r < r1; ++r) {
        const int es = offs[r], ee = offs[r + 1];
        const int d = ee - es;
        if (d == 0) continue;

        const float* __restrict__ prow = P + (size_t)r * HID;
        const float4 p0 = *(const float4*)(prow + j0);
        const float4 p1 = *(const float4*)(prow + 256 + j0);

        if (d <= 64) {
            float mysc = chunk_scores(Q, cols16, es, d, lane, j0,
                                      p0, p1, w0, w1, bias2);

            float m = mysc;
#pragma unroll
            for (int off = 32; off > 0; off >>= 1)
                m = fmaxf(m, __shfl_xor(m, off, 64));

            float ev = (lane < d) ? expf(mysc - m) : 0.0f;
            float ssum = ev;
#pragma unroll
            for (int off = 32; off > 0; off >>= 1)
                ssum += __shfl_xor(ssum, off, 64);

            if (lane < d) {
                float p = ev / ssum;
                float logits = logf(p) - log1pf(-p);   // +inf when p==1 (d==1)
                tmp[es + lane] = make_float2(mysc, logits);
            }
        } else {
            for (int base = 0; base < d; base += 64) {
                const int nch = (d - base < 64) ? d - base : 64;
                float mysc = chunk_scores(Q, cols16, es + base, nch, lane, j0,
                                          p0, p1, w0, w1, bias2);
                if (lane < nch) tmp[es + base + lane].x = mysc;
            }

            float m = -INFINITY;
            for (int j = lane; j < d; j += 64)
                m = fmaxf(m, tmp[es + j].x);
#pragma unroll
            for (int off = 32; off > 0; off >>= 1)
                m = fmaxf(m, __shfl_xor(m, off, 64));

            float ssum = 0.0f;
            for (int j = lane; j < d; j += 64)
                ssum += expf(tmp[es + j].x - m);
#pragma unroll
            for (int off = 32; off > 0; off >>= 1)
                ssum += __shfl_xor(ssum, off, 64);

            for (int j = lane; j < d; j += 64) {
                float s = tmp[es + j].x;
                float p = expf(s - m) / ssum;
                float logits = logf(p) - log1pf(-p);
                tmp[es + j] = make_float2(s, logits);
            }
        }
    }
}

// ---------------------------------------------------------------------------
__global__ __launch_bounds__(256) void unperm(
    const float2* __restrict__ tmp, const int* __restrict__ inv,
    const float* __restrict__ u, const int* __restrict__ edge_mask,
    const int* __restrict__ hierarchy,
    float* __restrict__ scores, float* __restrict__ out_y,
    float* __restrict__ out_mask, float* __restrict__ out_causal,
    float* __restrict__ out_spu)
{
    const int e = blockIdx.x * 256 + threadIdx.x;
    if (e >= N_EDGES) return;
    const float2 t = tmp[inv[e]];
    const float s = t.x;
    const float uu = u[e];
    const float L = logf(uu) - log1pf(-uu);
    const float y = 1.0f / (1.0f + expf(-(t.y + L)));
    const bool hard = y > 0.5f;                    // ST forward value == y_hard
    const int mm = hard ? (hierarchy[0] + 1) : edge_mask[e];
    scores[e]     = s;
    out_y[e]      = hard ? 1.0f : 0.0f;
    out_mask[e]   = (float)mm;
    out_causal[e] = (mm > 0)   ?  s : 0.0f;
    out_spu[e]    = (mm == -1) ? -s : 0.0f;
}

// ---------------------------------------------------------------------------
extern "C" void kernel_launch(void* const* d_in, const int* in_sizes, int n_in,
                              void* d_out, int out_size, void* d_ws, size_t ws_size,
                              hipStream_t stream) {
    const float* h_ptr = (const float*)d_in[0];
    const float* W1    = (const float*)d_in[1];
    const float* b1    = (const float*)d_in[2];
    const float* W2    = (const float*)d_in[3];
    const float* b2    = (const float*)d_in[4];
    const float* u     = (const float*)d_in[5];
    const int*   row   = (const int*)d_in[6];
    const int*   col   = (const int*)d_in[7];
    const int*   emask = (const int*)d_in[8];
    const int*   hier  = (const int*)d_in[9];

    float* out        = (float*)d_out;
    float* scores     = out;                        // [E]
    float* out_y      = out + (size_t)N_EDGES;      // [E]
    float* out_mask   = out + 2 * (size_t)N_EDGES;  // [E]
    float* out_causal = out + 3 * (size_t)N_EDGES;  // [E]
    float* out_spu    = out + 4 * (size_t)N_EDGES;  // [E]

    // workspace: P, Q fp32; packed hp1..3 bf16 [1250][4][64][8]; packed
    // wp1..3 bf16 [64][4][64][8]; small int arrays. tmp/cols16/inv ALIAS the
    // hp region (hp dead after gemm_mfma; first written by scatter_edges).
    float*          P      = (float*)d_ws;
    float*          Qm     = P + (size_t)N_NODES * HID;
    unsigned short* hp1    = (unsigned short*)(Qm + (size_t)N_NODES * HID);
    unsigned short* hp2    = hp1 + (size_t)N_NODES * EMB;
    unsigned short* hp3    = hp2 + (size_t)N_NODES * EMB;
    unsigned short* wp1    = hp3 + (size_t)N_NODES * EMB;
    unsigned short* wp2    = wp1 + 1024 * 128;
    unsigned short* wp3    = wp2 + 1024 * 128;
    int*            deg    = (int*)(wp3 + 1024 * 128);
    int*            cursor = deg + N_NODES;
    int*            offs   = cursor + N_NODES;      // [N_NODES+1]
    int*            part   = offs + N_NODES + 1;
    int*            totals = part + N_NODES;        // [NCHUNK]
    float2*         tmp    = (float2*)hp1;                      // [E] 2.56MB
    unsigned short* cols16 = (unsigned short*)(tmp + N_EDGES);  // [E] u16
    int*            inv    = (int*)(cols16 + N_EDGES);          // [E]

    hipLaunchKernelGGL(init_deg, dim3((N_NODES + 255) / 256), dim3(256), 0, stream,
                       deg, offs);

    hipLaunchKernelGGL(prep_pack, dim3(PREP_BLOCKS), dim3(256), 0, stream,
                       h_ptr, W1, hp1, hp2, hp3, wp1, wp2, wp3);

    hipLaunchKernelGGL(gemm_mfma, dim3(GH_BLOCKS), dim3(256), 0, stream,
                       hp1, hp2, hp3, wp1, wp2, wp3, b1, P, Qm, row, deg);

    hipLaunchKernelGGL(scan_part, dim3(NCHUNK), dim3(1024), 0, stream, deg, part, totals);
    hipLaunchKernelGGL(scan_apply, dim3(NCHUNK), dim3(1024), 0, stream,
                       part, totals, cursor, offs);
    hipLaunchKernelGGL(scatter_edges, dim3((N_EDGES + 255) / 256), dim3(256), 0, stream,
                       row, col, cursor, cols16, inv);

    hipLaunchKernelGGL(fused_edge, dim3(FE_BLOCKS), dim3(128), 0, stream,
                       P, Qm, W2, b2, cols16, offs, tmp);

    hipLaunchKernelGGL(unperm, dim3((N_EDGES + 255) / 256), dim3(256), 0, stream,
                       tmp, inv, u, emask, hier,
                       scores, out_y, out_mask, out_causal, out_spu);
}

// Round 6
// 262.297 us; speedup vs baseline: 1.2583x; 1.0649x over previous
//
#include <hip/hip_runtime.h>
#include <math.h>

#define N_NODES 20000
#define N_EDGES 320000
#define EMB 128
#define HID 512          // 4*EMB
#define NCHUNK ((N_NODES + 1023) / 1024)   // 20

// fused_edge geometry (round-2 champion)
#define RPW 4
#define WPB 2
#define RPB (RPW * WPB)                    // 8
#define FE_BLOCKS ((N_NODES + RPB - 1) / RPB)  // 2500

// MFMA gemm geometry: block tile 256(M) x 64(N), 4 waves of 64x64
#define GEMM_MT ((N_NODES + 255) / 256)    // 79
#define GEMM_NT 16                         // 1024 / 64
#define GEMM_MFMA_BLOCKS (GEMM_MT * GEMM_NT)   // 1264
#define HIST_BLOCKS ((N_EDGES + 255) / 256)    // 1250
#define GH_BLOCKS (GEMM_MFMA_BLOCKS + HIST_BLOCKS)  // 2514
#define N_HTILES (N_NODES / 16)            // 1250 (exact)

// prep block ranges: h-split pack, W-split pack, deg zero
#define PREP_H_BLOCKS 2500                 // 20000*128/4 float4 / 256thr
#define PREP_W_BLOCKS 64                   // 16384 threads (8 k per thread)
#define PREP_Z_BLOCKS ((N_NODES + 255) / 256)   // 79
#define PREP_BLOCKS (PREP_H_BLOCKS + PREP_W_BLOCKS + PREP_Z_BLOCKS)

typedef __attribute__((ext_vector_type(8))) short bf16x8;  // 8 bf16 = 4 VGPR
typedef __attribute__((ext_vector_type(4))) float f32x4;

#define MFMA16(a, b, c) __builtin_amdgcn_mfma_f32_16x16x32_bf16((a), (b), (c), 0, 0, 0)

// async global->LDS: per-lane GLOBAL source, wave-uniform LDS base + lane*16.
// (exact helper from round-3 — semantics harness-verified)
__device__ __forceinline__ void stage16(const unsigned short* g, unsigned short* l) {
    __builtin_amdgcn_global_load_lds(
        (const __attribute__((address_space(1))) void*)g,
        (__attribute__((address_space(3))) void*)l, 16, 0, 0);
}

// ---------------------------------------------------------------------------
// bf16x3 split helpers (round-to-nearest-even bf16; exact residual chain)
// ---------------------------------------------------------------------------
__device__ __forceinline__ unsigned short bf16rn(float x) {
    unsigned u = __builtin_bit_cast(unsigned, x);
    u += 0x7FFFu + ((u >> 16) & 1u);
    return (unsigned short)(u >> 16);
}
__device__ __forceinline__ float bf2f(unsigned short b) {
    unsigned u = ((unsigned)b) << 16;
    return __builtin_bit_cast(float, u);
}
__device__ __forceinline__ void split3(float x, unsigned short& s1,
                                       unsigned short& s2, unsigned short& s3) {
    s1 = bf16rn(x);
    float r = x - bf2f(s1);
    s2 = bf16rn(r);
    float r2 = r - bf2f(s2);
    s3 = bf16rn(r2);
}

// ---------------------------------------------------------------------------
// prep_pack: packed-fragment split writes + deg zeroing (init_deg folded in).
// Packed element (t, ks, lane, j) at offset (t*4+ks)*512 + lane*8 + j where
//   source row r = t*16 + (lane&15), k = ks*32 + (lane>>4)*8 + j.
// ---------------------------------------------------------------------------
__global__ __launch_bounds__(256) void prep_pack(
    const float* __restrict__ h, const float* __restrict__ W1,
    unsigned short* __restrict__ hp1, unsigned short* __restrict__ hp2,
    unsigned short* __restrict__ hp3,
    unsigned short* __restrict__ wp1, unsigned short* __restrict__ wp2,
    unsigned short* __restrict__ wp3,
    int* __restrict__ deg, int* __restrict__ offs)
{
    const int bid = blockIdx.x, tid = threadIdx.x;

    if (bid < PREP_H_BLOCKS) {
        const int i4 = bid * 256 + tid;              // float4 index, exact fit
        const float4 v = ((const float4*)h)[i4];
        const int r  = i4 >> 5;                      // 32 float4 per row
        const int k0 = (i4 & 31) << 2;
        const int t = r >> 4, rowi = r & 15;
        const int ks = k0 >> 5;
        const int ln = (((k0 >> 3) & 3) << 4) + rowi;
        const int j0 = k0 & 7;                       // 0 or 4 -> 8B aligned
        const size_t off = (size_t)((t * 4 + ks) * 512) + ln * 8 + j0;
        unsigned short a1[4], a2[4], a3[4];
        split3(v.x, a1[0], a2[0], a3[0]);
        split3(v.y, a1[1], a2[1], a3[1]);
        split3(v.z, a1[2], a2[2], a3[2]);
        split3(v.w, a1[3], a2[3], a3[3]);
#define PACK4(dst, a) { \
            uint2 pk; \
            pk.x = (unsigned)a[0] | ((unsigned)a[1] << 16); \
            pk.y = (unsigned)a[2] | ((unsigned)a[3] << 16); \
            *(uint2*)((dst) + off) = pk; }
        PACK4(hp1, a1); PACK4(hp2, a2); PACK4(hp3, a3);
#undef PACK4
        return;
    }

    if (bid < PREP_H_BLOCKS + PREP_W_BLOCKS) {
        // W path: thread handles 8 consecutive k for one output col n.
        // Reads coalesced across lanes (consecutive n); writes 16B contiguous.
        const int t = (bid - PREP_H_BLOCKS) * 256 + tid;   // 16384 exact
        const int n = t & 1023, kg = t >> 10;              // kg in [0,16)
        const int k0 = kg << 3;
        const int wrow0 = ((n >> 9) << 7) + k0;
        const int wcol  = n & 511;
        unsigned short s1[8], s2[8], s3[8];
#pragma unroll
        for (int j = 0; j < 8; ++j) {
            const float x = W1[(size_t)(wrow0 + j) * HID + wcol];
            split3(x, s1[j], s2[j], s3[j]);
        }
        const int tn = n >> 4, rown = n & 15;
        const int ks = k0 >> 5;
        const int ln = (((k0 >> 3) & 3) << 4) + rown;
        const size_t off = (size_t)((tn * 4 + ks) * 512) + ln * 8;
#define PACK8(dst, a) { \
            uint4 pk; \
            pk.x = (unsigned)a[0] | ((unsigned)a[1] << 16); \
            pk.y = (unsigned)a[2] | ((unsigned)a[3] << 16); \
            pk.z = (unsigned)a[4] | ((unsigned)a[5] << 16); \
            pk.w = (unsigned)a[6] | ((unsigned)a[7] << 16); \
            *(uint4*)((dst) + off) = pk; }
        PACK8(wp1, s1); PACK8(wp2, s2); PACK8(wp3, s3);
#undef PACK8
        return;
    }

    // deg zero path
    const int i = (bid - PREP_H_BLOCKS - PREP_W_BLOCKS) * 256 + tid;
    if (i < N_NODES) deg[i] = 0;
    if (i == 0) offs[N_NODES] = N_EDGES;
}

// ---------------------------------------------------------------------------
// gemm_mfma + histogram. O[20000][1024] = h @ [W1a|W1b], bf16x3-split MFMA
// (products 11,12,21,22,13,31 in fixed order -> fp32-accurate, bit-stable
// vs r4/r5 which passed).
// Block 256 thr / 4 waves stacked in M; block tile 256x64.
// B (64 cols x 128 K x 3 splits = 48 KB) staged ONCE to LDS via
// global_load_lds (zero VGPR cost), then ds_read_b128 per fragment.
// A: 12 VMEM frag loads per wave per ks, double-buffered in registers so the
// 96-MFMA block (~1860 cy) covers the ~600 cy latency of the next ks' loads.
// ---------------------------------------------------------------------------
__global__ __launch_bounds__(256, 2) void gemm_mfma(
    const unsigned short* __restrict__ hp1, const unsigned short* __restrict__ hp2,
    const unsigned short* __restrict__ hp3,
    const unsigned short* __restrict__ wp1, const unsigned short* __restrict__ wp2,
    const unsigned short* __restrict__ wp3,
    const float* __restrict__ b1, float* __restrict__ P, float* __restrict__ Q,
    const int* __restrict__ row, int* __restrict__ deg)
{
    const int bid = blockIdx.x;
    const int tid = threadIdx.x;

    if (bid >= GEMM_MFMA_BLOCKS) {
        // ---- histogram path ----
        const int e = (bid - GEMM_MFMA_BLOCKS) * 256 + tid;
        if (e < N_EDGES) atomicAdd(&deg[row[e]], 1);
        return;
    }

    __shared__ unsigned short bs[4][4][3][512];   // [jn][ks][split][1KB] = 48KB

    const int mt = bid >> 4, nt = bid & 15;   // 16 consecutive blocks share mt (A reuse in L2)
    const int lane = tid & 63, w = tid >> 6;
    const int l15 = lane & 15, l4 = lane >> 4;

    // ---- stage B: wave w stages its jn=w column sub-tile (12 chunks) ----
    {
        const int tn = nt * 4 + w;            // packed w-tile index (< 64)
        const unsigned short* wps0 = wp1;
        const unsigned short* wps1 = wp2;
        const unsigned short* wps2 = wp3;
#pragma unroll
        for (int ks = 0; ks < 4; ++ks) {
            const size_t so = (size_t)((tn * 4 + ks) * 512) + lane * 8;
            stage16(wps0 + so, &bs[w][ks][0][0]);
            stage16(wps1 + so, &bs[w][ks][1][0]);
            stage16(wps2 + so, &bs[w][ks][2][0]);
        }
    }

    // ---- A tile indices + ks=0 preload (issued before the barrier drain) ----
    int tA[4];
#pragma unroll
    for (int i = 0; i < 4; ++i) {
        int t = mt * 16 + w * 4 + i;
        tA[i] = (t < N_HTILES) ? t : N_HTILES - 1;   // clamp; stores guarded
    }
    size_t aoff[4];
#pragma unroll
    for (int i = 0; i < 4; ++i)
        aoff[i] = (size_t)(tA[i] * 4) * 512 + lane * 8;

    bf16x8 A1[4], A2[4], A3[4];
#pragma unroll
    for (int i = 0; i < 4; ++i) {
        A1[i] = *(const bf16x8*)(hp1 + aoff[i]);
        A2[i] = *(const bf16x8*)(hp2 + aoff[i]);
        A3[i] = *(const bf16x8*)(hp3 + aoff[i]);
    }

    f32x4 acc[4][4];
#pragma unroll
    for (int i = 0; i < 4; ++i)
#pragma unroll
        for (int j = 0; j < 4; ++j) acc[i][j] = (f32x4){0.f, 0.f, 0.f, 0.f};

    __syncthreads();   // drains vmcnt: B staged + A ks=0 resident

#pragma unroll
    for (int ks = 0; ks < 4; ++ks) {
        bf16x8 N1[4], N2[4], N3[4];
        if (ks < 3) {
            const size_t ko = (size_t)(ks + 1) * 512;
#pragma unroll
            for (int i = 0; i < 4; ++i) {
                N1[i] = *(const bf16x8*)(hp1 + aoff[i] + ko);
                N2[i] = *(const bf16x8*)(hp2 + aoff[i] + ko);
                N3[i] = *(const bf16x8*)(hp3 + aoff[i] + ko);
            }
        }
#pragma unroll
        for (int jn = 0; jn < 4; ++jn) {
            const unsigned short* bb = &bs[jn][ks][0][0] + lane * 8;
            const bf16x8 Ba1 = *(const bf16x8*)(bb);
            const bf16x8 Ba2 = *(const bf16x8*)(bb + 512);
            const bf16x8 Ba3 = *(const bf16x8*)(bb + 1024);
#pragma unroll
            for (int i = 0; i < 4; ++i) {
                acc[i][jn] = MFMA16(A1[i], Ba1, acc[i][jn]);
                acc[i][jn] = MFMA16(A1[i], Ba2, acc[i][jn]);
                acc[i][jn] = MFMA16(A2[i], Ba1, acc[i][jn]);
                acc[i][jn] = MFMA16(A2[i], Ba2, acc[i][jn]);
                acc[i][jn] = MFMA16(A1[i], Ba3, acc[i][jn]);
                acc[i][jn] = MFMA16(A3[i], Ba1, acc[i][jn]);
            }
        }
        if (ks < 3) {
#pragma unroll
            for (int i = 0; i < 4; ++i) {
                A1[i] = N1[i]; A2[i] = N2[i]; A3[i] = N3[i];
            }
        }
    }

    // store: D lane l, reg r -> row (l>>4)*4+r, col l&15 (m89-verified)
    const int rb0 = mt * 256 + w * 64;
#pragma unroll
    for (int jn = 0; jn < 4; ++jn) {
        const int n = nt * 64 + jn * 16 + l15;
        const bool isP = n < 512;
        float* __restrict__ dst = isP ? P : Q;
        const int col = n & 511;
        const float bias = isP ? b1[col] : 0.0f;
#pragma unroll
        for (int i = 0; i < 4; ++i) {
            const int rr0 = rb0 + i * 16 + l4 * 4;
#pragma unroll
            for (int r = 0; r < 4; ++r) {
                const int rr = rr0 + r;
                if (rr < N_NODES)
                    dst[(size_t)rr * HID + col] = acc[i][jn][r] + bias;
            }
        }
    }
}

// ---------------------------------------------------------------------------
__device__ __forceinline__ int wave_incl_scan(int v, int lane) {
#pragma unroll
    for (int off = 1; off < 64; off <<= 1) {
        int t = __shfl_up(v, off, 64);
        if (lane >= off) v += t;
    }
    return v;
}

__global__ __launch_bounds__(1024) void scan_part(const int* __restrict__ deg,
                                                  int* __restrict__ part,
                                                  int* __restrict__ totals) {
    __shared__ int wsum[16];
    const int tid = threadIdx.x, lane = tid & 63, w = tid >> 6;
    const int i = blockIdx.x * 1024 + tid;
    int v = (i < N_NODES) ? deg[i] : 0;
    int incl = wave_incl_scan(v, lane);
    if (lane == 63) wsum[w] = incl;
    __syncthreads();
    if (w == 0) {
        int x = (lane < 16) ? wsum[lane] : 0;
        int xs = wave_incl_scan(x, lane);
        if (lane < 16) wsum[lane] = xs - x;
        if (lane == 15) totals[blockIdx.x] = xs;
    }
    __syncthreads();
    if (i < N_NODES) part[i] = wsum[w] + incl - v;
}

__global__ __launch_bounds__(1024) void scan_apply(const int* __restrict__ part,
                                                   const int* __restrict__ totals,
                                                   int* __restrict__ cursor,
                                                   int* __restrict__ offs) {
    __shared__ int carry_s;
    const int tid = threadIdx.x;
    if (tid < 64) {
        int v = (tid < NCHUNK) ? totals[tid] : 0;
        int incl = wave_incl_scan(v, tid);
        if (tid == (int)blockIdx.x) carry_s = incl - v;   // exclusive carry
    }
    __syncthreads();
    const int i = blockIdx.x * 1024 + tid;
    if (i < N_NODES) {
        int o = part[i] + carry_s;
        cursor[i] = o;
        offs[i] = o;
    }
}

// ---------------------------------------------------------------------------
__global__ void scatter_edges(const int* __restrict__ row, const int* __restrict__ col,
                              int* __restrict__ cursor,
                              unsigned short* __restrict__ cols16,
                              int* __restrict__ inv) {
    int e = blockIdx.x * 256 + threadIdx.x;
    if (e >= N_EDGES) return;
    int r = row[e];
    int pos = atomicAdd(&cursor[r], 1);
    cols16[pos] = (unsigned short)col[e];
    inv[e] = pos;
}

// ---------------------------------------------------------------------------
// Fused edge phase — round-2 champion (101.5us, at its 8xXCD-L2-fill memory
// ceiling: FETCH pinned at 311MB across three structures).
// ---------------------------------------------------------------------------
__device__ __forceinline__ float dot8_relu(const float4 qa, const float4 qb,
                                           const float4 p0, const float4 p1,
                                           const float4 w0, const float4 w1) {
    float t = 0.0f;
    t = fmaf(fmaxf(p0.x + qa.x, 0.0f), w0.x, t);
    t = fmaf(fmaxf(p0.y + qa.y, 0.0f), w0.y, t);
    t = fmaf(fmaxf(p0.z + qa.z, 0.0f), w0.z, t);
    t = fmaf(fmaxf(p0.w + qa.w, 0.0f), w0.w, t);
    t = fmaf(fmaxf(p1.x + qb.x, 0.0f), w1.x, t);
    t = fmaf(fmaxf(p1.y + qb.y, 0.0f), w1.y, t);
    t = fmaf(fmaxf(p1.z + qb.z, 0.0f), w1.z, t);
    t = fmaf(fmaxf(p1.w + qb.w, 0.0f), w1.w, t);
    return t;
}

__device__ __forceinline__ float chunk_scores(
    const float* __restrict__ Q, const unsigned short* __restrict__ cols16,
    int es_base, int nch, int lane, int j0,
    const float4 p0, const float4 p1, const float4 w0, const float4 w1,
    float bias2)
{
    int mycol = 0;
    if (lane < nch) mycol = (int)cols16[es_base + lane];
    float mysc = -INFINITY;

#define QL2(k, bb, d0, d1) { \
        int c_ = __shfl(mycol, (bb) + (k), 64); \
        const float* __restrict__ q_ = Q + (size_t)c_ * HID; \
        d0 = *(const float4*)(q_ + j0); \
        d1 = *(const float4*)(q_ + 256 + j0); }

    float4 a00, a01, a10, a11;
    QL2(0, 0, a00, a01); QL2(1, 0, a10, a11);

    for (int b = 0; b < nch; b += 2) {
        float4 n00, n01, n10, n11;
        const bool more = (b + 2) < nch;
        if (more) { QL2(0, b + 2, n00, n01); QL2(1, b + 2, n10, n11); }

        float s0 = dot8_relu(a00, a01, p0, p1, w0, w1);
        float s1 = dot8_relu(a10, a11, p0, p1, w0, w1);

#pragma unroll
        for (int off = 32; off > 0; off >>= 1) {
            s0 += __shfl_xor(s0, off, 64);
            s1 += __shfl_xor(s1, off, 64);
        }

        const int k = lane - b;
        if ((unsigned)k < 2u && lane < nch) mysc = (k ? s1 : s0) + bias2;

        if (more) { a00 = n00; a01 = n01; a10 = n10; a11 = n11; }
    }
#undef QL2
    return mysc;
}

__global__ __launch_bounds__(128) void fused_edge(
    const float* __restrict__ P, const float* __restrict__ Q,
    const float* __restrict__ W2, const float* __restrict__ b2,
    const unsigned short* __restrict__ cols16, const int* __restrict__ offs,
    float2* __restrict__ tmp)
{
    const int tid = threadIdx.x, lane = tid & 63, w = tid >> 6;
    const int r0 = blockIdx.x * RPB + w * RPW;
    const int r1 = (r0 + RPW < N_NODES) ? r0 + RPW : N_NODES;
    const int j0 = lane << 2;

    const float4 w0 = *(const float4*)(W2 + j0);
    const float4 w1 = *(const float4*)(W2 + 256 + j0);
    const float bias2 = b2[0];

    for (int r = r0; r < r1; ++r) {
        const int es = offs[r], ee = offs[r + 1];
        const int d = ee - es;
        if (d == 0) continue;

        const float* __restrict__ prow = P + (size_t)r * HID;
        const float4 p0 = *(const float4*)(prow + j0);
        const float4 p1 = *(const float4*)(prow + 256 + j0);

        if (d <= 64) {
            float mysc = chunk_scores(Q, cols16, es, d, lane, j0,
                                      p0, p1, w0, w1, bias2);

            float m = mysc;
#pragma unroll
            for (int off = 32; off > 0; off >>= 1)
                m = fmaxf(m, __shfl_xor(m, off, 64));

            float ev = (lane < d) ? expf(mysc - m) : 0.0f;
            float ssum = ev;
#pragma unroll
            for (int off = 32; off > 0; off >>= 1)
                ssum += __shfl_xor(ssum, off, 64);

            if (lane < d) {
                float p = ev / ssum;
                float logits = logf(p) - log1pf(-p);   // +inf when p==1 (d==1)
                tmp[es + lane] = make_float2(mysc, logits);
            }
        } else {
            for (int base = 0; base < d; base += 64) {
                const int nch = (d - base < 64) ? d - base : 64;
                float mysc = chunk_scores(Q, cols16, es + base, nch, lane, j0,
                                          p0, p1, w0, w1, bias2);
                if (lane < nch) tmp[es + base + lane].x = mysc;
            }

            float m = -INFINITY;
            for (int j = lane; j < d; j += 64)
                m = fmaxf(m, tmp[es + j].x);
#pragma unroll
            for (int off = 32; off > 0; off >>= 1)
                m = fmaxf(m, __shfl_xor(m, off, 64));

            float ssum = 0.0f;
            for (int j = lane; j < d; j += 64)
                ssum += expf(tmp[es + j].x - m);
#pragma unroll
            for (int off = 32; off > 0; off >>= 1)
                ssum += __shfl_xor(ssum, off, 64);

            for (int j = lane; j < d; j += 64) {
                float s = tmp[es + j].x;
                float p = expf(s - m) / ssum;
                float logits = logf(p) - log1pf(-p);
                tmp[es + j] = make_float2(s, logits);
            }
        }
    }
}

// ---------------------------------------------------------------------------
__global__ __launch_bounds__(256) void unperm(
    const float2* __restrict__ tmp, const int* __restrict__ inv,
    const float* __restrict__ u, const int* __restrict__ edge_mask,
    const int* __restrict__ hierarchy,
    float* __restrict__ scores, float* __restrict__ out_y,
    float* __restrict__ out_mask, float* __restrict__ out_causal,
    float* __restrict__ out_spu)
{
    const int e = blockIdx.x * 256 + threadIdx.x;
    if (e >= N_EDGES) return;
    const float2 t = tmp[inv[e]];
    const float s = t.x;
    const float uu = u[e];
    const float L = logf(uu) - log1pf(-uu);
    const float y = 1.0f / (1.0f + expf(-(t.y + L)));
    const bool hard = y > 0.5f;                    // ST forward value == y_hard
    const int mm = hard ? (hierarchy[0] + 1) : edge_mask[e];
    scores[e]     = s;
    out_y[e]      = hard ? 1.0f : 0.0f;
    out_mask[e]   = (float)mm;
    out_causal[e] = (mm > 0)   ?  s : 0.0f;
    out_spu[e]    = (mm == -1) ? -s : 0.0f;
}

// ---------------------------------------------------------------------------
extern "C" void kernel_launch(void* const* d_in, const int* in_sizes, int n_in,
                              void* d_out, int out_size, void* d_ws, size_t ws_size,
                              hipStream_t stream) {
    const float* h_ptr = (const float*)d_in[0];
    const float* W1    = (const float*)d_in[1];
    const float* b1    = (const float*)d_in[2];
    const float* W2    = (const float*)d_in[3];
    const float* b2    = (const float*)d_in[4];
    const float* u     = (const float*)d_in[5];
    const int*   row   = (const int*)d_in[6];
    const int*   col   = (const int*)d_in[7];
    const int*   emask = (const int*)d_in[8];
    const int*   hier  = (const int*)d_in[9];

    float* out        = (float*)d_out;
    float* scores     = out;                        // [E]
    float* out_y      = out + (size_t)N_EDGES;      // [E]
    float* out_mask   = out + 2 * (size_t)N_EDGES;  // [E]
    float* out_causal = out + 3 * (size_t)N_EDGES;  // [E]
    float* out_spu    = out + 4 * (size_t)N_EDGES;  // [E]

    // workspace: P, Q fp32; packed hp1..3 bf16; packed wp1..3 bf16; ints.
    // tmp/cols16/inv ALIAS the hp region (hp dead after gemm_mfma; first
    // written by scatter_edges which runs after).
    float*          P      = (float*)d_ws;
    float*          Qm     = P + (size_t)N_NODES * HID;
    unsigned short* hp1    = (unsigned short*)(Qm + (size_t)N_NODES * HID);
    unsigned short* hp2    = hp1 + (size_t)N_NODES * EMB;
    unsigned short* hp3    = hp2 + (size_t)N_NODES * EMB;
    unsigned short* wp1    = hp3 + (size_t)N_NODES * EMB;
    unsigned short* wp2    = wp1 + 1024 * 128;
    unsigned short* wp3    = wp2 + 1024 * 128;
    int*            deg    = (int*)(wp3 + 1024 * 128);
    int*            cursor = deg + N_NODES;
    int*            offs   = cursor + N_NODES;      // [N_NODES+1]
    int*            part   = offs + N_NODES + 1;
    int*            totals = part + N_NODES;        // [NCHUNK]
    float2*         tmp    = (float2*)hp1;                      // [E] 2.56MB
    unsigned short* cols16 = (unsigned short*)(tmp + N_EDGES);  // [E] u16
    int*            inv    = (int*)(cols16 + N_EDGES);          // [E]

    hipLaunchKernelGGL(prep_pack, dim3(PREP_BLOCKS), dim3(256), 0, stream,
                       h_ptr, W1, hp1, hp2, hp3, wp1, wp2, wp3, deg, offs);

    hipLaunchKernelGGL(gemm_mfma, dim3(GH_BLOCKS), dim3(256), 0, stream,
                       hp1, hp2, hp3, wp1, wp2, wp3, b1, P, Qm, row, deg);

    hipLaunchKernelGGL(scan_part, dim3(NCHUNK), dim3(1024), 0, stream, deg, part, totals);
    hipLaunchKernelGGL(scan_apply, dim3(NCHUNK), dim3(1024), 0, stream,
                       part, totals, cursor, offs);
    hipLaunchKernelGGL(scatter_edges, dim3((N_EDGES + 255) / 256), dim3(256), 0, stream,
                       row, col, cursor, cols16, inv);

    hipLaunchKernelGGL(fused_edge, dim3(FE_BLOCKS), dim3(128), 0, stream,
                       P, Qm, W2, b2, cols16, offs, tmp);

    hipLaunchKernelGGL(unperm, dim3((N_EDGES + 255) / 256), dim3(256), 0, stream,
                       tmp, inv, u, emask, hier,
                       scores, out_y, out_mask, out_causal, out_spu);
}

// Round 7
// 253.690 us; speedup vs baseline: 1.3010x; 1.0339x over previous
//
#include <hip/hip_runtime.h>
#include <math.h>

#define N_NODES 20000
#define N_EDGES 320000
#define EMB 128
#define HID 512          // 4*EMB
#define NCHUNK ((N_NODES + 1023) / 1024)   // 20

// fused_edge geometry: 256-thr blocks (4 waves), each wave owns 2 rows.
// r6 post-mortem: grid size (not VGPR/LDS) capped occupancy at ~41%; same
// block count with 4 waves/block doubles available waves/CU.
#define RPW 2
#define WPB 4
#define RPB (RPW * WPB)                    // 8
#define FE_BLOCKS ((N_NODES + RPB - 1) / RPB)  // 2500

// MFMA gemm geometry: block tile 256(M) x 64(N), 4 waves of 64x64
#define GEMM_MT ((N_NODES + 255) / 256)    // 79
#define GEMM_NT 16                         // 1024 / 64
#define GEMM_MFMA_BLOCKS (GEMM_MT * GEMM_NT)   // 1264 = 8*158
#define HIST_BLOCKS ((N_EDGES + 255) / 256)    // 1250
#define GH_BLOCKS (GEMM_MFMA_BLOCKS + HIST_BLOCKS)  // 2514
#define N_HTILES (N_NODES / 16)            // 1250 (exact)

// prep block ranges: h-split pack, W-split pack, deg zero
#define PREP_H_BLOCKS 2500                 // 20000*128/4 float4 / 256thr
#define PREP_W_BLOCKS 64                   // 16384 threads (8 k per thread)
#define PREP_Z_BLOCKS ((N_NODES + 255) / 256)   // 79
#define PREP_BLOCKS (PREP_H_BLOCKS + PREP_W_BLOCKS + PREP_Z_BLOCKS)

typedef __attribute__((ext_vector_type(8))) short bf16x8;  // 8 bf16 = 4 VGPR
typedef __attribute__((ext_vector_type(4))) float f32x4;

#define MFMA16(a, b, c) __builtin_amdgcn_mfma_f32_16x16x32_bf16((a), (b), (c), 0, 0, 0)

// async global->LDS: per-lane GLOBAL source, wave-uniform LDS base + lane*16.
__device__ __forceinline__ void stage16(const unsigned short* g, unsigned short* l) {
    __builtin_amdgcn_global_load_lds(
        (const __attribute__((address_space(1))) void*)g,
        (__attribute__((address_space(3))) void*)l, 16, 0, 0);
}

// ---------------------------------------------------------------------------
// bf16x3 split helpers (round-to-nearest-even bf16; exact residual chain)
// ---------------------------------------------------------------------------
__device__ __forceinline__ unsigned short bf16rn(float x) {
    unsigned u = __builtin_bit_cast(unsigned, x);
    u += 0x7FFFu + ((u >> 16) & 1u);
    return (unsigned short)(u >> 16);
}
__device__ __forceinline__ float bf2f(unsigned short b) {
    unsigned u = ((unsigned)b) << 16;
    return __builtin_bit_cast(float, u);
}
__device__ __forceinline__ void split3(float x, unsigned short& s1,
                                       unsigned short& s2, unsigned short& s3) {
    s1 = bf16rn(x);
    float r = x - bf2f(s1);
    s2 = bf16rn(r);
    float r2 = r - bf2f(s2);
    s3 = bf16rn(r2);
}

// ---------------------------------------------------------------------------
// prep_pack: packed-fragment split writes + deg zeroing.
// Packed element (t, ks, lane, j) at offset (t*4+ks)*512 + lane*8 + j where
//   source row r = t*16 + (lane&15), k = ks*32 + (lane>>4)*8 + j.
// ---------------------------------------------------------------------------
__global__ __launch_bounds__(256) void prep_pack(
    const float* __restrict__ h, const float* __restrict__ W1,
    unsigned short* __restrict__ hp1, unsigned short* __restrict__ hp2,
    unsigned short* __restrict__ hp3,
    unsigned short* __restrict__ wp1, unsigned short* __restrict__ wp2,
    unsigned short* __restrict__ wp3,
    int* __restrict__ deg, int* __restrict__ offs)
{
    const int bid = blockIdx.x, tid = threadIdx.x;

    if (bid < PREP_H_BLOCKS) {
        const int i4 = bid * 256 + tid;              // float4 index, exact fit
        const float4 v = ((const float4*)h)[i4];
        const int r  = i4 >> 5;                      // 32 float4 per row
        const int k0 = (i4 & 31) << 2;
        const int t = r >> 4, rowi = r & 15;
        const int ks = k0 >> 5;
        const int ln = (((k0 >> 3) & 3) << 4) + rowi;
        const int j0 = k0 & 7;                       // 0 or 4 -> 8B aligned
        const size_t off = (size_t)((t * 4 + ks) * 512) + ln * 8 + j0;
        unsigned short a1[4], a2[4], a3[4];
        split3(v.x, a1[0], a2[0], a3[0]);
        split3(v.y, a1[1], a2[1], a3[1]);
        split3(v.z, a1[2], a2[2], a3[2]);
        split3(v.w, a1[3], a2[3], a3[3]);
#define PACK4(dst, a) { \
            uint2 pk; \
            pk.x = (unsigned)a[0] | ((unsigned)a[1] << 16); \
            pk.y = (unsigned)a[2] | ((unsigned)a[3] << 16); \
            *(uint2*)((dst) + off) = pk; }
        PACK4(hp1, a1); PACK4(hp2, a2); PACK4(hp3, a3);
#undef PACK4
        return;
    }

    if (bid < PREP_H_BLOCKS + PREP_W_BLOCKS) {
        // W path: thread handles 8 consecutive k for one output col n.
        const int t = (bid - PREP_H_BLOCKS) * 256 + tid;   // 16384 exact
        const int n = t & 1023, kg = t >> 10;              // kg in [0,16)
        const int k0 = kg << 3;
        const int wrow0 = ((n >> 9) << 7) + k0;
        const int wcol  = n & 511;
        unsigned short s1[8], s2[8], s3[8];
#pragma unroll
        for (int j = 0; j < 8; ++j) {
            const float x = W1[(size_t)(wrow0 + j) * HID + wcol];
            split3(x, s1[j], s2[j], s3[j]);
        }
        const int tn = n >> 4, rown = n & 15;
        const int ks = k0 >> 5;
        const int ln = (((k0 >> 3) & 3) << 4) + rown;
        const size_t off = (size_t)((tn * 4 + ks) * 512) + ln * 8;
#define PACK8(dst, a) { \
            uint4 pk; \
            pk.x = (unsigned)a[0] | ((unsigned)a[1] << 16); \
            pk.y = (unsigned)a[2] | ((unsigned)a[3] << 16); \
            pk.z = (unsigned)a[4] | ((unsigned)a[5] << 16); \
            pk.w = (unsigned)a[6] | ((unsigned)a[7] << 16); \
            *(uint4*)((dst) + off) = pk; }
        PACK8(wp1, s1); PACK8(wp2, s2); PACK8(wp3, s3);
#undef PACK8
        return;
    }

    // deg zero path
    const int i = (bid - PREP_H_BLOCKS - PREP_W_BLOCKS) * 256 + tid;
    if (i < N_NODES) deg[i] = 0;
    if (i == 0) offs[N_NODES] = N_EDGES;
}

// ---------------------------------------------------------------------------
// gemm_mfma + histogram. O[20000][1024] = h @ [W1a|W1b], bf16x3-split MFMA.
// Round-7 changes:
//  * XCD swizzle: dispatch bid -> XCD bid%8 (empirical round-robin); lb gives
//    each XCD a CONTIGUOUS logical range, so the 16 nt-blocks sharing an
//    A-tile (same mt) run on ONE XCD's L2 (~2MB A working set fits 4MB).
//  * MFMA order: product-outer / jn / i-inner. Consecutive MFMAs hit 16
//    different accumulators (dependency distance 1 -> 16). Per-acc product
//    order stays (11,12,21,22,13,31) -> bitwise-identical results.
// B (48 KB) staged once via global_load_lds; A reg-double-buffered per ks.
// ---------------------------------------------------------------------------
__global__ __launch_bounds__(256, 2) void gemm_mfma(
    const unsigned short* __restrict__ hp1, const unsigned short* __restrict__ hp2,
    const unsigned short* __restrict__ hp3,
    const unsigned short* __restrict__ wp1, const unsigned short* __restrict__ wp2,
    const unsigned short* __restrict__ wp3,
    const float* __restrict__ b1, float* __restrict__ P, float* __restrict__ Q,
    const int* __restrict__ row, int* __restrict__ deg)
{
    const int bid = blockIdx.x;
    const int tid = threadIdx.x;

    if (bid >= GEMM_MFMA_BLOCKS) {
        // ---- histogram path ----
        const int e = (bid - GEMM_MFMA_BLOCKS) * 256 + tid;
        if (e < N_EDGES) atomicAdd(&deg[row[e]], 1);
        return;
    }

    __shared__ unsigned short bs[4][4][3][512];   // [jn][ks][split][1KB] = 48KB

    // XCD-contiguous logical block id (1264 = 8*158, bijective)
    const int lb = (bid & 7) * (GEMM_MFMA_BLOCKS / 8) + (bid >> 3);
    const int mt = lb >> 4, nt = lb & 15;
    const int lane = tid & 63, w = tid >> 6;
    const int l15 = lane & 15, l4 = lane >> 4;

    // ---- stage B: wave w stages its jn=w column sub-tile (12 chunks) ----
    {
        const int tn = nt * 4 + w;            // packed w-tile index (< 64)
#pragma unroll
        for (int ks = 0; ks < 4; ++ks) {
            const size_t so = (size_t)((tn * 4 + ks) * 512) + lane * 8;
            stage16(wp1 + so, &bs[w][ks][0][0]);
            stage16(wp2 + so, &bs[w][ks][1][0]);
            stage16(wp3 + so, &bs[w][ks][2][0]);
        }
    }

    // ---- A tile indices + ks=0 preload ----
    int tA[4];
#pragma unroll
    for (int i = 0; i < 4; ++i) {
        int t = mt * 16 + w * 4 + i;
        tA[i] = (t < N_HTILES) ? t : N_HTILES - 1;   // clamp; stores guarded
    }
    size_t aoff[4];
#pragma unroll
    for (int i = 0; i < 4; ++i)
        aoff[i] = (size_t)(tA[i] * 4) * 512 + lane * 8;

    bf16x8 A1[4], A2[4], A3[4];
#pragma unroll
    for (int i = 0; i < 4; ++i) {
        A1[i] = *(const bf16x8*)(hp1 + aoff[i]);
        A2[i] = *(const bf16x8*)(hp2 + aoff[i]);
        A3[i] = *(const bf16x8*)(hp3 + aoff[i]);
    }

    f32x4 acc[4][4];
#pragma unroll
    for (int i = 0; i < 4; ++i)
#pragma unroll
        for (int j = 0; j < 4; ++j) acc[i][j] = (f32x4){0.f, 0.f, 0.f, 0.f};

    __syncthreads();   // drains vmcnt: B staged + A ks=0 resident

#pragma unroll
    for (int ks = 0; ks < 4; ++ks) {
        bf16x8 N1[4], N2[4], N3[4];
        if (ks < 3) {
            const size_t ko = (size_t)(ks + 1) * 512;
#pragma unroll
            for (int i = 0; i < 4; ++i) {
                N1[i] = *(const bf16x8*)(hp1 + aoff[i] + ko);
                N2[i] = *(const bf16x8*)(hp2 + aoff[i] + ko);
                N3[i] = *(const bf16x8*)(hp3 + aoff[i] + ko);
            }
        }
        // 6 split-products, p-outer / jn / i-inner
#define PROD(AA, SP) \
        { _Pragma("unroll") \
          for (int jn = 0; jn < 4; ++jn) { \
              const bf16x8 Bv = *(const bf16x8*)(&bs[jn][ks][SP][0] + lane * 8); \
              _Pragma("unroll") \
              for (int i = 0; i < 4; ++i) \
                  acc[i][jn] = MFMA16(AA[i], Bv, acc[i][jn]); \
          } }
        PROD(A1, 0) PROD(A1, 1) PROD(A2, 0) PROD(A2, 1) PROD(A1, 2) PROD(A3, 0)
#undef PROD
        if (ks < 3) {
#pragma unroll
            for (int i = 0; i < 4; ++i) {
                A1[i] = N1[i]; A2[i] = N2[i]; A3[i] = N3[i];
            }
        }
    }

    // store: D lane l, reg r -> row (l>>4)*4+r, col l&15 (m89-verified)
    const int rb0 = mt * 256 + w * 64;
#pragma unroll
    for (int jn = 0; jn < 4; ++jn) {
        const int n = nt * 64 + jn * 16 + l15;
        const bool isP = n < 512;
        float* __restrict__ dst = isP ? P : Q;
        const int col = n & 511;
        const float bias = isP ? b1[col] : 0.0f;
#pragma unroll
        for (int i = 0; i < 4; ++i) {
            const int rr0 = rb0 + i * 16 + l4 * 4;
#pragma unroll
            for (int r = 0; r < 4; ++r) {
                const int rr = rr0 + r;
                if (rr < N_NODES)
                    dst[(size_t)rr * HID + col] = acc[i][jn][r] + bias;
            }
        }
    }
}

// ---------------------------------------------------------------------------
__device__ __forceinline__ int wave_incl_scan(int v, int lane) {
#pragma unroll
    for (int off = 1; off < 64; off <<= 1) {
        int t = __shfl_up(v, off, 64);
        if (lane >= off) v += t;
    }
    return v;
}

__global__ __launch_bounds__(1024) void scan_part(const int* __restrict__ deg,
                                                  int* __restrict__ part,
                                                  int* __restrict__ totals) {
    __shared__ int wsum[16];
    const int tid = threadIdx.x, lane = tid & 63, w = tid >> 6;
    const int i = blockIdx.x * 1024 + tid;
    int v = (i < N_NODES) ? deg[i] : 0;
    int incl = wave_incl_scan(v, lane);
    if (lane == 63) wsum[w] = incl;
    __syncthreads();
    if (w == 0) {
        int x = (lane < 16) ? wsum[lane] : 0;
        int xs = wave_incl_scan(x, lane);
        if (lane < 16) wsum[lane] = xs - x;
        if (lane == 15) totals[blockIdx.x] = xs;
    }
    __syncthreads();
    if (i < N_NODES) part[i] = wsum[w] + incl - v;
}

__global__ __launch_bounds__(1024) void scan_apply(const int* __restrict__ part,
                                                   const int* __restrict__ totals,
                                                   int* __restrict__ cursor,
                                                   int* __restrict__ offs) {
    __shared__ int carry_s;
    const int tid = threadIdx.x;
    if (tid < 64) {
        int v = (tid < NCHUNK) ? totals[tid] : 0;
        int incl = wave_incl_scan(v, tid);
        if (tid == (int)blockIdx.x) carry_s = incl - v;   // exclusive carry
    }
    __syncthreads();
    const int i = blockIdx.x * 1024 + tid;
    if (i < N_NODES) {
        int o = part[i] + carry_s;
        cursor[i] = o;
        offs[i] = o;
    }
}

// ---------------------------------------------------------------------------
__global__ void scatter_edges(const int* __restrict__ row, const int* __restrict__ col,
                              int* __restrict__ cursor,
                              unsigned short* __restrict__ cols16,
                              int* __restrict__ inv) {
    int e = blockIdx.x * 256 + threadIdx.x;
    if (e >= N_EDGES) return;
    int r = row[e];
    int pos = atomicAdd(&cursor[r], 1);
    cols16[pos] = (unsigned short)col[e];
    inv[e] = pos;
}

// ---------------------------------------------------------------------------
// Fused edge phase — r2 inner structure, r7 geometry (4 waves/block, 2 rows
// per wave). FETCH pinned at 311MB; this tests whether occupancy (grid-limited
// at 41% through r6) or the per-CU miss path caps the 3.2 TB/s fill.
// ---------------------------------------------------------------------------
__device__ __forceinline__ float dot8_relu(const float4 qa, const float4 qb,
                                           const float4 p0, const float4 p1,
                                           const float4 w0, const float4 w1) {
    float t = 0.0f;
    t = fmaf(fmaxf(p0.x + qa.x, 0.0f), w0.x, t);
    t = fmaf(fmaxf(p0.y + qa.y, 0.0f), w0.y, t);
    t = fmaf(fmaxf(p0.z + qa.z, 0.0f), w0.z, t);
    t = fmaf(fmaxf(p0.w + qa.w, 0.0f), w0.w, t);
    t = fmaf(fmaxf(p1.x + qb.x, 0.0f), w1.x, t);
    t = fmaf(fmaxf(p1.y + qb.y, 0.0f), w1.y, t);
    t = fmaf(fmaxf(p1.z + qb.z, 0.0f), w1.z, t);
    t = fmaf(fmaxf(p1.w + qb.w, 0.0f), w1.w, t);
    return t;
}

__device__ __forceinline__ float chunk_scores(
    const float* __restrict__ Q, const unsigned short* __restrict__ cols16,
    int es_base, int nch, int lane, int j0,
    const float4 p0, const float4 p1, const float4 w0, const float4 w1,
    float bias2)
{
    int mycol = 0;
    if (lane < nch) mycol = (int)cols16[es_base + lane];
    float mysc = -INFINITY;

#define QL2(k, bb, d0, d1) { \
        int c_ = __shfl(mycol, (bb) + (k), 64); \
        const float* __restrict__ q_ = Q + (size_t)c_ * HID; \
        d0 = *(const float4*)(q_ + j0); \
        d1 = *(const float4*)(q_ + 256 + j0); }

    float4 a00, a01, a10, a11;
    QL2(0, 0, a00, a01); QL2(1, 0, a10, a11);

    for (int b = 0; b < nch; b += 2) {
        float4 n00, n01, n10, n11;
        const bool more = (b + 2) < nch;
        if (more) { QL2(0, b + 2, n00, n01); QL2(1, b + 2, n10, n11); }

        float s0 = dot8_relu(a00, a01, p0, p1, w0, w1);
        float s1 = dot8_relu(a10, a11, p0, p1, w0, w1);

#pragma unroll
        for (int off = 32; off > 0; off >>= 1) {
            s0 += __shfl_xor(s0, off, 64);
            s1 += __shfl_xor(s1, off, 64);
        }

        const int k = lane - b;
        if ((unsigned)k < 2u && lane < nch) mysc = (k ? s1 : s0) + bias2;

        if (more) { a00 = n00; a01 = n01; a10 = n10; a11 = n11; }
    }
#undef QL2
    return mysc;
}

__global__ __launch_bounds__(256) void fused_edge(
    const float* __restrict__ P, const float* __restrict__ Q,
    const float* __restrict__ W2, const float* __restrict__ b2,
    const unsigned short* __restrict__ cols16, const int* __restrict__ offs,
    float2* __restrict__ tmp)
{
    const int tid = threadIdx.x, lane = tid & 63, w = tid >> 6;
    const int r0 = blockIdx.x * RPB + w * RPW;
    const int r1 = (r0 + RPW < N_NODES) ? r0 + RPW : N_NODES;
    const int j0 = lane << 2;

    const float4 w0 = *(const float4*)(W2 + j0);
    const float4 w1 = *(const float4*)(W2 + 256 + j0);
    const float bias2 = b2[0];

    for (int r = r0; r < r1; ++r) {
        const int es = offs[r], ee = offs[r + 1];
        const int d = ee - es;
        if (d == 0) continue;

        const float* __restrict__ prow = P + (size_t)r * HID;
        const float4 p0 = *(const float4*)(prow + j0);
        const float4 p1 = *(const float4*)(prow + 256 + j0);

        if (d <= 64) {
            float mysc = chunk_scores(Q, cols16, es, d, lane, j0,
                                      p0, p1, w0, w1, bias2);

            float m = mysc;
#pragma unroll
            for (int off = 32; off > 0; off >>= 1)
                m = fmaxf(m, __shfl_xor(m, off, 64));

            float ev = (lane < d) ? expf(mysc - m) : 0.0f;
            float ssum = ev;
#pragma unroll
            for (int off = 32; off > 0; off >>= 1)
                ssum += __shfl_xor(ssum, off, 64);

            if (lane < d) {
                float p = ev / ssum;
                float logits = logf(p) - log1pf(-p);   // +inf when p==1 (d==1)
                tmp[es + lane] = make_float2(mysc, logits);
            }
        } else {
            for (int base = 0; base < d; base += 64) {
                const int nch = (d - base < 64) ? d - base : 64;
                float mysc = chunk_scores(Q, cols16, es + base, nch, lane, j0,
                                          p0, p1, w0, w1, bias2);
                if (lane < nch) tmp[es + base + lane].x = mysc;
            }

            float m = -INFINITY;
            for (int j = lane; j < d; j += 64)
                m = fmaxf(m, tmp[es + j].x);
#pragma unroll
            for (int off = 32; off > 0; off >>= 1)
                m = fmaxf(m, __shfl_xor(m, off, 64));

            float ssum = 0.0f;
            for (int j = lane; j < d; j += 64)
                ssum += expf(tmp[es + j].x - m);
#pragma unroll
            for (int off = 32; off > 0; off >>= 1)
                ssum += __shfl_xor(ssum, off, 64);

            for (int j = lane; j < d; j += 64) {
                float s = tmp[es + j].x;
                float p = expf(s - m) / ssum;
                float logits = logf(p) - log1pf(-p);
                tmp[es + j] = make_float2(s, logits);
            }
        }
    }
}

// ---------------------------------------------------------------------------
__global__ __launch_bounds__(256) void unperm(
    const float2* __restrict__ tmp, const int* __restrict__ inv,
    const float* __restrict__ u, const int* __restrict__ edge_mask,
    const int* __restrict__ hierarchy,
    float* __restrict__ scores, float* __restrict__ out_y,
    float* __restrict__ out_mask, float* __restrict__ out_causal,
    float* __restrict__ out_spu)
{
    const int e = blockIdx.x * 256 + threadIdx.x;
    if (e >= N_EDGES) return;
    const float2 t = tmp[inv[e]];
    const float s = t.x;
    const float uu = u[e];
    const float L = logf(uu) - log1pf(-uu);
    const float y = 1.0f / (1.0f + expf(-(t.y + L)));
    const bool hard = y > 0.5f;                    // ST forward value == y_hard
    const int mm = hard ? (hierarchy[0] + 1) : edge_mask[e];
    scores[e]     = s;
    out_y[e]      = hard ? 1.0f : 0.0f;
    out_mask[e]   = (float)mm;
    out_causal[e] = (mm > 0)   ?  s : 0.0f;
    out_spu[e]    = (mm == -1) ? -s : 0.0f;
}

// ---------------------------------------------------------------------------
extern "C" void kernel_launch(void* const* d_in, const int* in_sizes, int n_in,
                              void* d_out, int out_size, void* d_ws, size_t ws_size,
                              hipStream_t stream) {
    const float* h_ptr = (const float*)d_in[0];
    const float* W1    = (const float*)d_in[1];
    const float* b1    = (const float*)d_in[2];
    const float* W2    = (const float*)d_in[3];
    const float* b2    = (const float*)d_in[4];
    const float* u     = (const float*)d_in[5];
    const int*   row   = (const int*)d_in[6];
    const int*   col   = (const int*)d_in[7];
    const int*   emask = (const int*)d_in[8];
    const int*   hier  = (const int*)d_in[9];

    float* out        = (float*)d_out;
    float* scores     = out;                        // [E]
    float* out_y      = out + (size_t)N_EDGES;      // [E]
    float* out_mask   = out + 2 * (size_t)N_EDGES;  // [E]
    float* out_causal = out + 3 * (size_t)N_EDGES;  // [E]
    float* out_spu    = out + 4 * (size_t)N_EDGES;  // [E]

    // workspace: P, Q fp32; packed hp1..3 bf16; packed wp1..3 bf16; ints.
    // tmp/cols16/inv ALIAS the hp region (hp dead after gemm_mfma; first
    // written by scatter_edges which runs after).
    float*          P      = (float*)d_ws;
    float*          Qm     = P + (size_t)N_NODES * HID;
    unsigned short* hp1    = (unsigned short*)(Qm + (size_t)N_NODES * HID);
    unsigned short* hp2    = hp1 + (size_t)N_NODES * EMB;
    unsigned short* hp3    = hp2 + (size_t)N_NODES * EMB;
    unsigned short* wp1    = hp3 + (size_t)N_NODES * EMB;
    unsigned short* wp2    = wp1 + 1024 * 128;
    unsigned short* wp3    = wp2 + 1024 * 128;
    int*            deg    = (int*)(wp3 + 1024 * 128);
    int*            cursor = deg + N_NODES;
    int*            offs   = cursor + N_NODES;      // [N_NODES+1]
    int*            part   = offs + N_NODES + 1;
    int*            totals = part + N_NODES;        // [NCHUNK]
    float2*         tmp    = (float2*)hp1;                      // [E] 2.56MB
    unsigned short* cols16 = (unsigned short*)(tmp + N_EDGES);  // [E] u16
    int*            inv    = (int*)(cols16 + N_EDGES);          // [E]

    hipLaunchKernelGGL(prep_pack, dim3(PREP_BLOCKS), dim3(256), 0, stream,
                       h_ptr, W1, hp1, hp2, hp3, wp1, wp2, wp3, deg, offs);

    hipLaunchKernelGGL(gemm_mfma, dim3(GH_BLOCKS), dim3(256), 0, stream,
                       hp1, hp2, hp3, wp1, wp2, wp3, b1, P, Qm, row, deg);

    hipLaunchKernelGGL(scan_part, dim3(NCHUNK), dim3(1024), 0, stream, deg, part, totals);
    hipLaunchKernelGGL(scan_apply, dim3(NCHUNK), dim3(1024), 0, stream,
                       part, totals, cursor, offs);
    hipLaunchKernelGGL(scatter_edges, dim3((N_EDGES + 255) / 256), dim3(256), 0, stream,
                       row, col, cursor, cols16, inv);

    hipLaunchKernelGGL(fused_edge, dim3(FE_BLOCKS), dim3(256), 0, stream,
                       P, Qm, W2, b2, cols16, offs, tmp);

    hipLaunchKernelGGL(unperm, dim3((N_EDGES + 255) / 256), dim3(256), 0, stream,
                       tmp, inv, u, emask, hier,
                       scores, out_y, out_mask, out_causal, out_spu);
}